// Round 1
// baseline (303.376 us; speedup 1.0000x reference)
//
#include <hip/hip_runtime.h>
#include <hip/hip_bf16.h>

// ---------------------------------------------------------------------------
// AttentionBlockWithSelfAttention on MI355X (gfx950)
// B=4, Cin=128, Fi=64, H=W=64, N=4096, d_qk=8
//
// k1 prep:     fold BN into conv weights -> bf16 Wcat[64x256], Wqkv[80x64]
// k2 conv_qkv: c = relu(Wcat @ [g;x] + bias)  (MFMA, bf16 in / f32 acc)
//              Q,K [B][N][8] bf16 ; V [B][64][N] bf16 (channel-major)
// k3 attn:     flash attention (Tq=64/block, 4 waves x 16q), fused epilogue
// ---------------------------------------------------------------------------

typedef short bf16x8 __attribute__((ext_vector_type(8)));
typedef float f32x4 __attribute__((ext_vector_type(4)));

__device__ __forceinline__ unsigned short f2b(float f) {
  unsigned u = __builtin_bit_cast(unsigned, f);
  u = (u + 0x7FFFu + ((u >> 16) & 1u)) >> 16;   // RNE f32 -> bf16
  return (unsigned short)u;
}

#define EPSV 1e-5f

// ---- workspace layout (bytes, all offsets 256-aligned) ----
#define WCAT_OFF   0u                    // 64*256 bf16  = 32768
#define WQKV_OFF   32768u                // 80*64  bf16  = 10240
#define BIASC_OFF  44032u                // 64 f32
#define BIASQ_OFF  44288u                // 80 f32
#define PSIW_OFF   44608u                // 64 f32
#define SCAL_OFF   44864u                // scalars f32
#define C_OFF      45056u                // 4*64*4096 f32 = 4194304
#define Q_OFF      (C_OFF + 4194304u)    // 4*4096*8 bf16 = 262144
#define K_OFF      (Q_OFF + 262144u)
#define V_OFF      (K_OFF + 262144u)     // 4*64*4096 bf16 = 2097152

// ===========================================================================
__global__ __launch_bounds__(256) void prep_kernel(
    const float* __restrict__ wg_w, const float* __restrict__ wg_b,
    const float* __restrict__ bng_w, const float* __restrict__ bng_b,
    const float* __restrict__ bng_m, const float* __restrict__ bng_v,
    const float* __restrict__ wx_w, const float* __restrict__ wx_b,
    const float* __restrict__ bnx_w, const float* __restrict__ bnx_b,
    const float* __restrict__ bnx_m, const float* __restrict__ bnx_v,
    const float* __restrict__ q_w, const float* __restrict__ q_b,
    const float* __restrict__ k_w, const float* __restrict__ k_b,
    const float* __restrict__ v_w, const float* __restrict__ v_b,
    const float* __restrict__ psi_w, const float* __restrict__ psi_b,
    const float* __restrict__ bnp_w, const float* __restrict__ bnp_b,
    const float* __restrict__ bnp_m, const float* __restrict__ bnp_v,
    const float* __restrict__ sa_gamma,
    unsigned short* __restrict__ Wcat, unsigned short* __restrict__ Wqkv,
    float* __restrict__ bias_c, float* __restrict__ bias_q,
    float* __restrict__ psi_w2, float* __restrict__ scal)
{
  const int t = threadIdx.x;
  // Wcat: rows o<64, k<128 -> inv_g*wg_w ; k>=128 -> inv_x*wx_w
  for (int idx = t; idx < 64 * 256; idx += 256) {
    int o = idx >> 8, k = idx & 255;
    float wv;
    if (k < 128) {
      float inv = bng_w[o] * rsqrtf(bng_v[o] + EPSV);
      wv = wg_w[o * 128 + k] * inv;
    } else {
      float inv = bnx_w[o] * rsqrtf(bnx_v[o] + EPSV);
      wv = wx_w[o * 128 + (k - 128)] * inv;
    }
    Wcat[idx] = f2b(wv);
  }
  // Wqkv: rows 0..7 q_w, 8..15 k_w, 16..79 v_w
  for (int idx = t; idx < 80 * 64; idx += 256) {
    int r = idx >> 6, k = idx & 63;
    float wv;
    if (r < 8)       wv = q_w[r * 64 + k];
    else if (r < 16) wv = k_w[(r - 8) * 64 + k];
    else             wv = v_w[(r - 16) * 64 + k];
    Wqkv[idx] = f2b(wv);
  }
  if (t < 64) {
    int o = t;
    float invg = bng_w[o] * rsqrtf(bng_v[o] + EPSV);
    float invx = bnx_w[o] * rsqrtf(bnx_v[o] + EPSV);
    bias_c[o] = (wg_b[o] - bng_m[o]) * invg + bng_b[o]
              + (wx_b[o] - bnx_m[o]) * invx + bnx_b[o];
    float invp = bnp_w[0] * rsqrtf(bnp_v[0] + EPSV);
    psi_w2[o] = psi_w[o] * invp;
  }
  if (t < 80) {
    bias_q[t] = (t < 8) ? q_b[t] : (t < 16 ? k_b[t - 8] : v_b[t - 16]);
  }
  if (t == 0) {
    float invp = bnp_w[0] * rsqrtf(bnp_v[0] + EPSV);
    scal[0] = sa_gamma[0];
    scal[1] = (psi_b[0] - bnp_m[0]) * invp + bnp_b[0];
  }
}

// ===========================================================================
// conv_qkv: one block per (b, 64-point tile). 4 waves.
__global__ __launch_bounds__(256) void conv_qkv_kernel(
    const float* __restrict__ g, const float* __restrict__ x,
    const unsigned short* __restrict__ Wcat, const unsigned short* __restrict__ Wqkv,
    const float* __restrict__ bias_c, const float* __restrict__ bias_q,
    float* __restrict__ c_out, unsigned short* __restrict__ Qb,
    unsigned short* __restrict__ Kb, unsigned short* __restrict__ Vb)
{
  __shared__ __attribute__((aligned(16))) unsigned short xt[64][264];   // [n][k] bf16, pad 8
  __shared__ __attribute__((aligned(16))) unsigned short clds[64][72];  // [n][o] bf16, pad 8

  const int t = threadIdx.x;
  const int bid = blockIdx.x;
  const int b = bid >> 6;
  const int n0 = (bid & 63) << 6;

  // ---- stage [g;x] tile, transposed to [n][k] bf16 ----
  #pragma unroll
  for (int i = 0; i < 16; ++i) {
    int ci = t + 256 * i;            // 0..4095
    int row = ci >> 4;               // k-channel 0..255
    int col4 = ci & 15;              // float4 index along n
    const float* src = (row < 128)
        ? (g + ((size_t)(b * 128 + row)) * 4096 + n0 + col4 * 4)
        : (x + ((size_t)(b * 128 + (row - 128))) * 4096 + n0 + col4 * 4);
    float4 v = *(const float4*)src;
    int n = col4 * 4;
    xt[n + 0][row] = f2b(v.x);
    xt[n + 1][row] = f2b(v.y);
    xt[n + 2][row] = f2b(v.z);
    xt[n + 3][row] = f2b(v.w);
  }
  __syncthreads();

  const int l = t & 63, w = t >> 6;
  const int l15 = l & 15, lg = l >> 4;

  // ---- conv MFMA: wave w owns output rows [16w,16w+16), 4 n-subtiles ----
  f32x4 acc[4];
  f32x4 zf = {0.f, 0.f, 0.f, 0.f};
  acc[0] = acc[1] = acc[2] = acc[3] = zf;
  const int orow = w * 16 + l15;
  #pragma unroll
  for (int ks = 0; ks < 8; ++ks) {
    bf16x8 af = *(const bf16x8*)(Wcat + orow * 256 + ks * 32 + lg * 8);
    #pragma unroll
    for (int ns = 0; ns < 4; ++ns) {
      bf16x8 bfv = *(const bf16x8*)(&xt[ns * 16 + l15][ks * 32 + lg * 8]);
      acc[ns] = __builtin_amdgcn_mfma_f32_16x16x32_bf16(af, bfv, acc[ns], 0, 0, 0);
    }
  }
  // bias + relu; store c (f32 global, channel-major) + clds (bf16 [n][o])
  #pragma unroll
  for (int r = 0; r < 4; ++r) {
    int o = w * 16 + lg * 4 + r;
    float bc = bias_c[o];
    #pragma unroll
    for (int ns = 0; ns < 4; ++ns) {
      float cv = fmaxf(acc[ns][r] + bc, 0.f);
      int n = ns * 16 + l15;
      c_out[((size_t)(b * 64 + o)) * 4096 + n0 + n] = cv;
      clds[n][o] = f2b(cv);
    }
  }
  __syncthreads();

  // ---- QKV MFMA: wave w owns n-subtile w; 5 row-tiles of Wqkv ----
  const int ngl = n0 + w * 16 + l15;
  #pragma unroll
  for (int t5 = 0; t5 < 5; ++t5) {
    f32x4 a2 = zf;
    #pragma unroll
    for (int kk = 0; kk < 2; ++kk) {
      bf16x8 af = *(const bf16x8*)(Wqkv + (t5 * 16 + l15) * 64 + kk * 32 + lg * 8);
      bf16x8 bfv = *(const bf16x8*)(&clds[w * 16 + l15][kk * 32 + lg * 8]);
      a2 = __builtin_amdgcn_mfma_f32_16x16x32_bf16(af, bfv, a2, 0, 0, 0);
    }
    #pragma unroll
    for (int r = 0; r < 4; ++r) {
      int row = t5 * 16 + lg * 4 + r;
      float val = a2[r] + bias_q[row];
      if (t5 == 0) {
        if (row < 8) Qb[(((size_t)b << 12) + ngl) * 8 + row] = f2b(val);
        else         Kb[(((size_t)b << 12) + ngl) * 8 + (row - 8)] = f2b(val);
      } else {
        int vch = (t5 - 1) * 16 + lg * 4 + r;
        Vb[((size_t)(b * 64 + vch)) * 4096 + ngl] = f2b(val);
      }
    }
  }
}

// ===========================================================================
// attn: flash attention + fused epilogue. One block per (b, 64-q tile).
__global__ __launch_bounds__(256) void attn_kernel(
    const unsigned short* __restrict__ Qb, const unsigned short* __restrict__ Kb,
    const unsigned short* __restrict__ Vb, const float* __restrict__ c_in,
    const float* __restrict__ xin, const float* __restrict__ psi_w2,
    const float* __restrict__ scal, float* __restrict__ out)
{
  __shared__ __attribute__((aligned(16))) unsigned short klds[64][8];    // [m][d]
  __shared__ __attribute__((aligned(16))) unsigned short vlds[64][72];   // [ch][m] pad 8
  __shared__ __attribute__((aligned(16))) unsigned short plds[4][16][72];// per-wave [q][m]
  __shared__ float psi_lds[64];

  const int t = threadIdx.x;
  const int bid = blockIdx.x;
  const int b = bid >> 6;
  const int n0 = (bid & 63) << 6;
  const int l = t & 63, w = t >> 6;
  const int l15 = l & 15, lg = l >> 4;

  // Q fragment: lanes 0-15 hold q[n][0..7]; lanes 16-63 zero (k>=8 padding).
  bf16x8 qf = {0, 0, 0, 0, 0, 0, 0, 0};
  if (lg == 0)
    qf = *(const bf16x8*)(Qb + (((size_t)b << 12) + n0 + w * 16 + l15) * 8);

  f32x4 zf = {0.f, 0.f, 0.f, 0.f};
  f32x4 O[4];
  O[0] = O[1] = O[2] = O[3] = zf;
  float m_run[4] = {-INFINITY, -INFINITY, -INFINITY, -INFINITY};
  float l_run[4] = {0.f, 0.f, 0.f, 0.f};

  for (int m0 = 0; m0 < 4096; m0 += 64) {
    // ---- stage K (1KB) and V (9KB) tiles ----
    if (t < 64)
      *(int4*)(&klds[t][0]) = *(const int4*)(Kb + (((size_t)b << 12) + m0 + t) * 8);
    #pragma unroll
    for (int i = 0; i < 2; ++i) {
      int ci = t + 256 * i;          // 0..511
      int row = ci >> 3, off = ci & 7;
      *(int4*)(&vlds[row][off * 8]) =
          *(const int4*)(Vb + ((size_t)(b * 64 + row)) * 4096 + m0 + off * 8);
    }
    __syncthreads();

    // ---- energy: E[16q x 64m] in 4 tiles ----
    f32x4 e[4];
    #pragma unroll
    for (int mt = 0; mt < 4; ++mt) {
      bf16x8 kf = *(const bf16x8*)(&klds[mt * 16 + l15][0]);
      e[mt] = __builtin_amdgcn_mfma_f32_16x16x32_bf16(qf, kf, zf, 0, 0, 0);
    }

    // ---- online softmax (per q-row; rows live in 16-lane groups) ----
    #pragma unroll
    for (int r = 0; r < 4; ++r) {
      float vm = fmaxf(fmaxf(e[0][r], e[1][r]), fmaxf(e[2][r], e[3][r]));
      vm = fmaxf(vm, __shfl_xor(vm, 1));
      vm = fmaxf(vm, __shfl_xor(vm, 2));
      vm = fmaxf(vm, __shfl_xor(vm, 4));
      vm = fmaxf(vm, __shfl_xor(vm, 8));
      float nm = fmaxf(m_run[r], vm);
      float sc = __expf(m_run[r] - nm);
      float s = 0.f;
      #pragma unroll
      for (int mt = 0; mt < 4; ++mt) {
        float p = __expf(e[mt][r] - nm);
        e[mt][r] = p;
        s += p;
      }
      s += __shfl_xor(s, 1);
      s += __shfl_xor(s, 2);
      s += __shfl_xor(s, 4);
      s += __shfl_xor(s, 8);
      l_run[r] = l_run[r] * sc + s;
      m_run[r] = nm;
      #pragma unroll
      for (int mt = 0; mt < 4; ++mt)
        plds[w][lg * 4 + r][mt * 16 + l15] = f2b(e[mt][r]);
      #pragma unroll
      for (int ct = 0; ct < 4; ++ct) O[ct][r] *= sc;
    }

    // ---- PV: O[16q x 64ch] += P @ V ----
    #pragma unroll
    for (int ct = 0; ct < 4; ++ct) {
      #pragma unroll
      for (int kk = 0; kk < 2; ++kk) {
        bf16x8 pa = *(const bf16x8*)(&plds[w][l15][kk * 32 + lg * 8]);
        bf16x8 vb = *(const bf16x8*)(&vlds[ct * 16 + l15][kk * 32 + lg * 8]);
        O[ct] = __builtin_amdgcn_mfma_f32_16x16x32_bf16(pa, vb, O[ct], 0, 0, 0);
      }
    }
    __syncthreads();
  }

  // ---- normalize ----
  #pragma unroll
  for (int r = 0; r < 4; ++r) {
    float inv = 1.f / l_run[r];
    #pragma unroll
    for (int ct = 0; ct < 4; ++ct) O[ct][r] *= inv;
  }

  // ---- epilogue: attended = gamma*O + c ; psi = sigmoid(psi_w2 . attended + psi_c)
  const float gamma = scal[0], psi_c = scal[1];
  float psum[4] = {0.f, 0.f, 0.f, 0.f};
  #pragma unroll
  for (int ct = 0; ct < 4; ++ct) {
    int ch = ct * 16 + l15;
    float pw = psi_w2[ch];
    #pragma unroll
    for (int r = 0; r < 4; ++r) {
      int ngl = n0 + w * 16 + lg * 4 + r;
      float att = gamma * O[ct][r] + c_in[((size_t)(b * 64 + ch)) * 4096 + ngl];
      psum[r] += pw * att;
    }
  }
  #pragma unroll
  for (int r = 0; r < 4; ++r) {
    float s = psum[r];
    s += __shfl_xor(s, 1);
    s += __shfl_xor(s, 2);
    s += __shfl_xor(s, 4);
    s += __shfl_xor(s, 8);
    if (l15 == 0) {
      float z = s + psi_c;
      psi_lds[w * 16 + lg * 4 + r] = 1.f / (1.f + __expf(-z));
    }
  }
  __syncthreads();

  // ---- out = x * psi (128 channels x 64 points) ----
  #pragma unroll
  for (int i = 0; i < 8; ++i) {
    int ci = t + 256 * i;            // 0..2047
    int f = ci >> 4, col4 = ci & 15;
    size_t off = ((size_t)(b * 128 + f)) * 4096 + n0 + col4 * 4;
    float4 xv = *(const float4*)(xin + off);
    float4 ov;
    ov.x = xv.x * psi_lds[col4 * 4 + 0];
    ov.y = xv.y * psi_lds[col4 * 4 + 1];
    ov.z = xv.z * psi_lds[col4 * 4 + 2];
    ov.w = xv.w * psi_lds[col4 * 4 + 3];
    *(float4*)(out + off) = ov;
  }
}

// ===========================================================================
extern "C" void kernel_launch(void* const* d_in, const int* in_sizes, int n_in,
                              void* d_out, int out_size, void* d_ws, size_t ws_size,
                              hipStream_t stream) {
  (void)in_sizes; (void)n_in; (void)out_size; (void)ws_size;
  const float* g     = (const float*)d_in[0];
  const float* x     = (const float*)d_in[1];
  const float* wg_w  = (const float*)d_in[2];
  const float* wg_b  = (const float*)d_in[3];
  const float* bng_w = (const float*)d_in[4];
  const float* bng_b = (const float*)d_in[5];
  const float* bng_m = (const float*)d_in[6];
  const float* bng_v = (const float*)d_in[7];
  const float* wx_w  = (const float*)d_in[8];
  const float* wx_b  = (const float*)d_in[9];
  const float* bnx_w = (const float*)d_in[10];
  const float* bnx_b = (const float*)d_in[11];
  const float* bnx_m = (const float*)d_in[12];
  const float* bnx_v = (const float*)d_in[13];
  const float* q_w   = (const float*)d_in[14];
  const float* q_b   = (const float*)d_in[15];
  const float* k_w   = (const float*)d_in[16];
  const float* k_b   = (const float*)d_in[17];
  const float* v_w   = (const float*)d_in[18];
  const float* v_b   = (const float*)d_in[19];
  const float* sa_g  = (const float*)d_in[20];
  const float* psi_w = (const float*)d_in[21];
  const float* psi_b = (const float*)d_in[22];
  const float* bnp_w = (const float*)d_in[23];
  const float* bnp_b = (const float*)d_in[24];
  const float* bnp_m = (const float*)d_in[25];
  const float* bnp_v = (const float*)d_in[26];
  float* out = (float*)d_out;

  char* ws = (char*)d_ws;
  unsigned short* Wcat = (unsigned short*)(ws + WCAT_OFF);
  unsigned short* Wqkv = (unsigned short*)(ws + WQKV_OFF);
  float* bias_c = (float*)(ws + BIASC_OFF);
  float* bias_q = (float*)(ws + BIASQ_OFF);
  float* psiw2  = (float*)(ws + PSIW_OFF);
  float* scal   = (float*)(ws + SCAL_OFF);
  float* c_buf  = (float*)(ws + C_OFF);
  unsigned short* Qb = (unsigned short*)(ws + Q_OFF);
  unsigned short* Kb = (unsigned short*)(ws + K_OFF);
  unsigned short* Vb = (unsigned short*)(ws + V_OFF);

  hipLaunchKernelGGL(prep_kernel, dim3(1), dim3(256), 0, stream,
                     wg_w, wg_b, bng_w, bng_b, bng_m, bng_v,
                     wx_w, wx_b, bnx_w, bnx_b, bnx_m, bnx_v,
                     q_w, q_b, k_w, k_b, v_w, v_b,
                     psi_w, psi_b, bnp_w, bnp_b, bnp_m, bnp_v, sa_g,
                     Wcat, Wqkv, bias_c, bias_q, psiw2, scal);

  hipLaunchKernelGGL(conv_qkv_kernel, dim3(256), dim3(256), 0, stream,
                     g, x, Wcat, Wqkv, bias_c, bias_q, c_buf, Qb, Kb, Vb);

  hipLaunchKernelGGL(attn_kernel, dim3(256), dim3(256), 0, stream,
                     Qb, Kb, Vb, c_buf, x, psiw2, scal, out);
}

// Round 2
// 188.927 us; speedup vs baseline: 1.6058x; 1.6058x over previous
//
#include <hip/hip_runtime.h>
#include <hip/hip_bf16.h>

// ---------------------------------------------------------------------------
// AttentionBlockWithSelfAttention on MI355X (gfx950)
// B=4, Cin=128, Fi=64, H=W=64, N=4096, d_qk=8
//
// k1 prep:       fold BN into conv weights (17 blocks)
// k2 conv_qkv:   c = relu(Wcat @ [g;x] + b)  (512 blocks, n-tile=32)
// k3 attn_part:  flash attention, KV split x4 -> partial O,m,l (1024 blocks)
// k4 combine:    merge partials + fused epilogue (psi, out = x*psi)
// ---------------------------------------------------------------------------

typedef short bf16x8 __attribute__((ext_vector_type(8)));
typedef unsigned short u16x8 __attribute__((ext_vector_type(8)));
typedef unsigned short u16x4 __attribute__((ext_vector_type(4)));
typedef float f32x4 __attribute__((ext_vector_type(4)));

__device__ __forceinline__ unsigned short f2b(float f) {
  unsigned u = __builtin_bit_cast(unsigned, f);
  u = (u + 0x7FFFu + ((u >> 16) & 1u)) >> 16;   // RNE f32 -> bf16
  return (unsigned short)u;
}

#define EPSV 1e-5f

// ---- workspace layout (bytes) ----
#define WCAT_OFF   0u                    // 64*256 bf16
#define WQKV_OFF   32768u                // 80*64 bf16
#define BIASC_OFF  44032u
#define BIASQ_OFF  44288u
#define PSIW_OFF   44608u
#define SCAL_OFF   44864u
#define C_OFF      45056u                // 4*64*4096 f32 = 4194304
#define Q_OFF      (C_OFF + 4194304u)    // 4*4096*8 bf16
#define K_OFF      (Q_OFF + 262144u)
#define V_OFF      (K_OFF + 262144u)     // 4*64*4096 bf16 = 2097152
#define OPART_OFF  (V_OFF + 2097152u)    // 16*4096*64 f32 = 16777216
#define ML_OFF     (OPART_OFF + 16777216u) // 16*4096*2 f32

// ===========================================================================
__global__ __launch_bounds__(256) void prep_kernel(
    const float* __restrict__ wg_w, const float* __restrict__ wg_b,
    const float* __restrict__ bng_w, const float* __restrict__ bng_b,
    const float* __restrict__ bng_m, const float* __restrict__ bng_v,
    const float* __restrict__ wx_w, const float* __restrict__ wx_b,
    const float* __restrict__ bnx_w, const float* __restrict__ bnx_b,
    const float* __restrict__ bnx_m, const float* __restrict__ bnx_v,
    const float* __restrict__ q_w, const float* __restrict__ q_b,
    const float* __restrict__ k_w, const float* __restrict__ k_b,
    const float* __restrict__ v_w, const float* __restrict__ v_b,
    const float* __restrict__ psi_w, const float* __restrict__ psi_b,
    const float* __restrict__ bnp_w, const float* __restrict__ bnp_b,
    const float* __restrict__ bnp_m, const float* __restrict__ bnp_v,
    const float* __restrict__ sa_gamma,
    unsigned short* __restrict__ Wcat, unsigned short* __restrict__ Wqkv,
    float* __restrict__ bias_c, float* __restrict__ bias_q,
    float* __restrict__ psi_w2, float* __restrict__ scal)
{
  const int t = threadIdx.x;
  const int bid = blockIdx.x;
  if (bid < 16) {
    // Wcat rows o = bid*4 + (t>>6); k = (t&63)*4  (chunks never straddle 128)
    int o = bid * 4 + (t >> 6);
    int k = (t & 63) * 4;
    float inv;
    const float* src;
    if (k < 128) {
      inv = bng_w[o] * rsqrtf(bng_v[o] + EPSV);
      src = wg_w + o * 128 + k;
    } else {
      inv = bnx_w[o] * rsqrtf(bnx_v[o] + EPSV);
      src = wx_w + o * 128 + (k - 128);
    }
    float4 wv = *(const float4*)src;
    u16x4 pk;
    pk[0] = f2b(wv.x * inv); pk[1] = f2b(wv.y * inv);
    pk[2] = f2b(wv.z * inv); pk[3] = f2b(wv.w * inv);
    *(u16x4*)(Wcat + o * 256 + k) = pk;
    return;
  }
  // block 16: Wqkv + biases + scalars
  for (int idx = t; idx < 80 * 64; idx += 256) {
    int r = idx >> 6, k = idx & 63;
    float wv;
    if (r < 8)       wv = q_w[r * 64 + k];
    else if (r < 16) wv = k_w[(r - 8) * 64 + k];
    else             wv = v_w[(r - 16) * 64 + k];
    Wqkv[idx] = f2b(wv);
  }
  if (t < 64) {
    int o = t;
    float invg = bng_w[o] * rsqrtf(bng_v[o] + EPSV);
    float invx = bnx_w[o] * rsqrtf(bnx_v[o] + EPSV);
    bias_c[o] = (wg_b[o] - bng_m[o]) * invg + bng_b[o]
              + (wx_b[o] - bnx_m[o]) * invx + bnx_b[o];
    float invp = bnp_w[0] * rsqrtf(bnp_v[0] + EPSV);
    psi_w2[o] = psi_w[o] * invp;
  }
  if (t < 80)
    bias_q[t] = (t < 8) ? q_b[t] : (t < 16 ? k_b[t - 8] : v_b[t - 16]);
  if (t == 0) {
    float invp = bnp_w[0] * rsqrtf(bnp_v[0] + EPSV);
    scal[0] = sa_gamma[0];
    scal[1] = (psi_b[0] - bnp_m[0]) * invp + bnp_b[0];
  }
}

// ===========================================================================
// conv_qkv: one block per (b, 32-point tile). 512 blocks, 4 waves.
__global__ __launch_bounds__(256) void conv_qkv_kernel(
    const float* __restrict__ g, const float* __restrict__ x,
    const unsigned short* __restrict__ Wcat, const unsigned short* __restrict__ Wqkv,
    const float* __restrict__ bias_c, const float* __restrict__ bias_q,
    float* __restrict__ c_out, unsigned short* __restrict__ Qb,
    unsigned short* __restrict__ Kb, unsigned short* __restrict__ Vb)
{
  __shared__ __attribute__((aligned(16))) unsigned short xt[32][264];   // [n][k], pad 8
  __shared__ __attribute__((aligned(16))) unsigned short clds[32][72];  // [n][o], pad 8

  const int t = threadIdx.x;
  const int bid = blockIdx.x;
  const int b = bid >> 7;
  const int n0 = (bid & 127) << 5;

  // ---- stage [g;x] tile transposed: 8 rows x float4 -> 4x ds_write_b128 ----
  {
    const int col4 = t & 7;          // n offset = col4*4
    const int rowg = t >> 3;         // rows rowg*8 .. +7
    float4 v[8];
    #pragma unroll
    for (int rr = 0; rr < 8; ++rr) {
      int row = rowg * 8 + rr;
      const float* src = (row < 128)
          ? (g + ((size_t)(b * 128 + row)) * 4096 + n0 + col4 * 4)
          : (x + ((size_t)(b * 128 + (row - 128))) * 4096 + n0 + col4 * 4);
      v[rr] = *(const float4*)src;
    }
    #pragma unroll
    for (int j = 0; j < 4; ++j) {
      u16x8 pk;
      #pragma unroll
      for (int rr = 0; rr < 8; ++rr)
        pk[rr] = f2b(((const float*)&v[rr])[j]);
      *(u16x8*)(&xt[col4 * 4 + j][rowg * 8]) = pk;
    }
  }
  __syncthreads();

  const int l = t & 63, w = t >> 6;
  const int l15 = l & 15, lg = l >> 4;
  f32x4 zf = {0.f, 0.f, 0.f, 0.f};

  // ---- conv MFMA: wave w owns o-rows [16w,16w+16), 2 n-subtiles ----
  f32x4 acc[2];
  acc[0] = acc[1] = zf;
  const int orow = w * 16 + l15;
  #pragma unroll
  for (int ks = 0; ks < 8; ++ks) {
    bf16x8 af = *(const bf16x8*)(Wcat + orow * 256 + ks * 32 + lg * 8);
    #pragma unroll
    for (int ns = 0; ns < 2; ++ns) {
      bf16x8 bfv = *(const bf16x8*)(&xt[ns * 16 + l15][ks * 32 + lg * 8]);
      acc[ns] = __builtin_amdgcn_mfma_f32_16x16x32_bf16(af, bfv, acc[ns], 0, 0, 0);
    }
  }
  #pragma unroll
  for (int r = 0; r < 4; ++r) {
    int o = w * 16 + lg * 4 + r;
    float bc = bias_c[o];
    #pragma unroll
    for (int ns = 0; ns < 2; ++ns) {
      float cv = fmaxf(acc[ns][r] + bc, 0.f);
      int n = ns * 16 + l15;
      c_out[((size_t)(b * 64 + o)) * 4096 + n0 + n] = cv;
      clds[n][o] = f2b(cv);
    }
  }
  __syncthreads();

  // ---- QKV MFMA: 10 tiles (5 row-tiles x 2 n-subtiles) over 4 waves ----
  #pragma unroll
  for (int i = 0; i < 3; ++i) {
    int tau = w + 4 * i;
    if (tau >= 10) break;
    int t5 = tau % 5, ns = tau / 5;
    f32x4 a2 = zf;
    #pragma unroll
    for (int kk = 0; kk < 2; ++kk) {
      bf16x8 af = *(const bf16x8*)(Wqkv + (t5 * 16 + l15) * 64 + kk * 32 + lg * 8);
      bf16x8 bfv = *(const bf16x8*)(&clds[ns * 16 + l15][kk * 32 + lg * 8]);
      a2 = __builtin_amdgcn_mfma_f32_16x16x32_bf16(af, bfv, a2, 0, 0, 0);
    }
    #pragma unroll
    for (int r = 0; r < 4; ++r) {
      int row = t5 * 16 + lg * 4 + r;
      int ngl = n0 + ns * 16 + l15;
      float val = a2[r] + bias_q[row];
      if (t5 == 0) {
        if (row < 8) Qb[(((size_t)b << 12) + ngl) * 8 + row] = f2b(val);
        else         Kb[(((size_t)b << 12) + ngl) * 8 + (row - 8)] = f2b(val);
      } else {
        int vch = (t5 - 1) * 16 + lg * 4 + r;
        Vb[((size_t)(b * 64 + vch)) * 4096 + ngl] = f2b(val);
      }
    }
  }
}

// ===========================================================================
// attn_partial: flash attention over one KV chunk of 1024. 1024 blocks.
__global__ __launch_bounds__(256) void attn_partial_kernel(
    const unsigned short* __restrict__ Qb, const unsigned short* __restrict__ Kb,
    const unsigned short* __restrict__ Vb,
    float* __restrict__ Opart, float* __restrict__ ml)
{
  __shared__ __attribute__((aligned(16))) unsigned short klds[64][8];
  __shared__ __attribute__((aligned(16))) unsigned short vlds[64][72];
  __shared__ __attribute__((aligned(16))) unsigned short plds[4][16][72];

  const int t = threadIdx.x;
  const int bid = blockIdx.x;
  const int qt = bid & 63;
  const int b = (bid >> 6) & 3;
  const int ci = bid >> 8;            // KV chunk 0..3
  const int n0 = qt << 6;
  const int l = t & 63, w = t >> 6;
  const int l15 = l & 15, lg = l >> 4;

  bf16x8 qf = {0, 0, 0, 0, 0, 0, 0, 0};
  if (lg == 0)
    qf = *(const bf16x8*)(Qb + (((size_t)b << 12) + n0 + w * 16 + l15) * 8);

  f32x4 zf = {0.f, 0.f, 0.f, 0.f};
  f32x4 O[4];
  O[0] = O[1] = O[2] = O[3] = zf;
  float m_run[4] = {-INFINITY, -INFINITY, -INFINITY, -INFINITY};
  float l_run[4] = {0.f, 0.f, 0.f, 0.f};

  const int m_lo = ci << 10, m_hi = (ci + 1) << 10;
  for (int m0 = m_lo; m0 < m_hi; m0 += 64) {
    if (t < 64)
      *(int4*)(&klds[t][0]) = *(const int4*)(Kb + (((size_t)b << 12) + m0 + t) * 8);
    #pragma unroll
    for (int i = 0; i < 2; ++i) {
      int ci2 = t + 256 * i;
      int row = ci2 >> 3, off = ci2 & 7;
      *(int4*)(&vlds[row][off * 8]) =
          *(const int4*)(Vb + ((size_t)(b * 64 + row)) * 4096 + m0 + off * 8);
    }
    __syncthreads();

    f32x4 e[4];
    #pragma unroll
    for (int mt = 0; mt < 4; ++mt) {
      bf16x8 kf = *(const bf16x8*)(&klds[mt * 16 + l15][0]);
      e[mt] = __builtin_amdgcn_mfma_f32_16x16x32_bf16(qf, kf, zf, 0, 0, 0);
    }

    #pragma unroll
    for (int r = 0; r < 4; ++r) {
      float vm = fmaxf(fmaxf(e[0][r], e[1][r]), fmaxf(e[2][r], e[3][r]));
      vm = fmaxf(vm, __shfl_xor(vm, 1));
      vm = fmaxf(vm, __shfl_xor(vm, 2));
      vm = fmaxf(vm, __shfl_xor(vm, 4));
      vm = fmaxf(vm, __shfl_xor(vm, 8));
      float nm = fmaxf(m_run[r], vm);
      float sc = __expf(m_run[r] - nm);
      float s = 0.f;
      #pragma unroll
      for (int mt = 0; mt < 4; ++mt) {
        float p = __expf(e[mt][r] - nm);
        e[mt][r] = p;
        s += p;
      }
      s += __shfl_xor(s, 1);
      s += __shfl_xor(s, 2);
      s += __shfl_xor(s, 4);
      s += __shfl_xor(s, 8);
      l_run[r] = l_run[r] * sc + s;
      m_run[r] = nm;
      #pragma unroll
      for (int mt = 0; mt < 4; ++mt)
        plds[w][lg * 4 + r][mt * 16 + l15] = f2b(e[mt][r]);
      #pragma unroll
      for (int ct = 0; ct < 4; ++ct) O[ct][r] *= sc;
    }

    #pragma unroll
    for (int ct = 0; ct < 4; ++ct) {
      #pragma unroll
      for (int kk = 0; kk < 2; ++kk) {
        bf16x8 pa = *(const bf16x8*)(&plds[w][l15][kk * 32 + lg * 8]);
        bf16x8 vb = *(const bf16x8*)(&vlds[ct * 16 + l15][kk * 32 + lg * 8]);
        O[ct] = __builtin_amdgcn_mfma_f32_16x16x32_bf16(pa, vb, O[ct], 0, 0, 0);
      }
    }
    __syncthreads();
  }

  // ---- store partials (unnormalized O + m,l) ----
  const size_t pb = ((size_t)(ci * 4 + b)) << 12;
  #pragma unroll
  for (int ct = 0; ct < 4; ++ct) {
    int ch = ct * 16 + l15;
    #pragma unroll
    for (int r = 0; r < 4; ++r) {
      int qg = n0 + w * 16 + lg * 4 + r;
      Opart[(pb + qg) * 64 + ch] = O[ct][r];
    }
  }
  if (l15 == 0) {
    #pragma unroll
    for (int r = 0; r < 4; ++r) {
      int qg = n0 + w * 16 + lg * 4 + r;
      float2 mv;
      mv.x = m_run[r]; mv.y = l_run[r];
      *(float2*)(ml + (pb + qg) * 2) = mv;
    }
  }
}

// ===========================================================================
// combine: merge 4 KV-chunk partials, fused epilogue. 256 blocks.
__global__ __launch_bounds__(256) void combine_kernel(
    const float* __restrict__ Opart, const float* __restrict__ ml,
    const float* __restrict__ c_in, const float* __restrict__ xin,
    const float* __restrict__ psi_w2, const float* __restrict__ scal,
    float* __restrict__ out)
{
  __shared__ __attribute__((aligned(16))) float c_lds[64][68];  // [ch][n], pad 4
  __shared__ float psi_lds[64];

  const int t = threadIdx.x;
  const int bid = blockIdx.x;
  const int b = bid >> 6;
  const int n0 = (bid & 63) << 6;

  // stage c tile [64ch][64n]
  #pragma unroll
  for (int i = 0; i < 4; ++i) {
    int idx = t + 256 * i;
    int ch = idx >> 4, c4 = idx & 15;
    float4 cv = *(const float4*)(c_in + ((size_t)(b * 64 + ch)) * 4096 + n0 + c4 * 4);
    *(float4*)(&c_lds[ch][c4 * 4]) = cv;
  }
  __syncthreads();

  const int q = t >> 2, cg = t & 3;
  const int qg = n0 + q;

  float m[4], li[4];
  float M = -INFINITY;
  #pragma unroll
  for (int ci = 0; ci < 4; ++ci) {
    float2 v = *(const float2*)(ml + ((((size_t)(ci * 4 + b)) << 12) + qg) * 2);
    m[ci] = v.x; li[ci] = v.y;
    M = fmaxf(M, v.x);
  }
  float L = 0.f, wgt[4];
  #pragma unroll
  for (int ci = 0; ci < 4; ++ci) {
    wgt[ci] = __expf(m[ci] - M);
    L += wgt[ci] * li[ci];
  }
  float4 o4[4];
  o4[0] = o4[1] = o4[2] = o4[3] = make_float4(0.f, 0.f, 0.f, 0.f);
  #pragma unroll
  for (int ci = 0; ci < 4; ++ci) {
    const float* base = Opart + ((((size_t)(ci * 4 + b)) << 12) + qg) * 64 + cg * 16;
    float wv = wgt[ci];
    #pragma unroll
    for (int k = 0; k < 4; ++k) {
      float4 p = *(const float4*)(base + k * 4);
      o4[k].x += wv * p.x; o4[k].y += wv * p.y;
      o4[k].z += wv * p.z; o4[k].w += wv * p.w;
    }
  }
  const float invL = 1.f / L;
  const float gamma = scal[0], psi_c = scal[1];
  float ps = 0.f;
  #pragma unroll
  for (int k = 0; k < 4; ++k) {
    const float* op = (const float*)&o4[k];
    #pragma unroll
    for (int jj = 0; jj < 4; ++jj) {
      int ch = cg * 16 + k * 4 + jj;
      ps += psi_w2[ch] * (gamma * (op[jj] * invL) + c_lds[ch][q]);
    }
  }
  ps += __shfl_xor(ps, 1);
  ps += __shfl_xor(ps, 2);
  if (cg == 0)
    psi_lds[q] = 1.f / (1.f + __expf(-(ps + psi_c)));
  __syncthreads();

  // out = x * psi
  #pragma unroll
  for (int i = 0; i < 8; ++i) {
    int idx = t + 256 * i;
    int f = idx >> 4, c4 = idx & 15;
    size_t off = ((size_t)(b * 128 + f)) * 4096 + n0 + c4 * 4;
    float4 xv = *(const float4*)(xin + off);
    float4 ov;
    ov.x = xv.x * psi_lds[c4 * 4 + 0];
    ov.y = xv.y * psi_lds[c4 * 4 + 1];
    ov.z = xv.z * psi_lds[c4 * 4 + 2];
    ov.w = xv.w * psi_lds[c4 * 4 + 3];
    *(float4*)(out + off) = ov;
  }
}

// ===========================================================================
extern "C" void kernel_launch(void* const* d_in, const int* in_sizes, int n_in,
                              void* d_out, int out_size, void* d_ws, size_t ws_size,
                              hipStream_t stream) {
  (void)in_sizes; (void)n_in; (void)out_size; (void)ws_size;
  const float* g     = (const float*)d_in[0];
  const float* x     = (const float*)d_in[1];
  const float* wg_w  = (const float*)d_in[2];
  const float* wg_b  = (const float*)d_in[3];
  const float* bng_w = (const float*)d_in[4];
  const float* bng_b = (const float*)d_in[5];
  const float* bng_m = (const float*)d_in[6];
  const float* bng_v = (const float*)d_in[7];
  const float* wx_w  = (const float*)d_in[8];
  const float* wx_b  = (const float*)d_in[9];
  const float* bnx_w = (const float*)d_in[10];
  const float* bnx_b = (const float*)d_in[11];
  const float* bnx_m = (const float*)d_in[12];
  const float* bnx_v = (const float*)d_in[13];
  const float* q_w   = (const float*)d_in[14];
  const float* q_b   = (const float*)d_in[15];
  const float* k_w   = (const float*)d_in[16];
  const float* k_b   = (const float*)d_in[17];
  const float* v_w   = (const float*)d_in[18];
  const float* v_b   = (const float*)d_in[19];
  const float* sa_g  = (const float*)d_in[20];
  const float* psi_w = (const float*)d_in[21];
  const float* psi_b = (const float*)d_in[22];
  const float* bnp_w = (const float*)d_in[23];
  const float* bnp_b = (const float*)d_in[24];
  const float* bnp_m = (const float*)d_in[25];
  const float* bnp_v = (const float*)d_in[26];
  float* out = (float*)d_out;

  char* ws = (char*)d_ws;
  unsigned short* Wcat = (unsigned short*)(ws + WCAT_OFF);
  unsigned short* Wqkv = (unsigned short*)(ws + WQKV_OFF);
  float* bias_c = (float*)(ws + BIASC_OFF);
  float* bias_q = (float*)(ws + BIASQ_OFF);
  float* psiw2  = (float*)(ws + PSIW_OFF);
  float* scal   = (float*)(ws + SCAL_OFF);
  float* c_buf  = (float*)(ws + C_OFF);
  unsigned short* Qb = (unsigned short*)(ws + Q_OFF);
  unsigned short* Kb = (unsigned short*)(ws + K_OFF);
  unsigned short* Vb = (unsigned short*)(ws + V_OFF);
  float* Opart = (float*)(ws + OPART_OFF);
  float* mlb   = (float*)(ws + ML_OFF);

  hipLaunchKernelGGL(prep_kernel, dim3(17), dim3(256), 0, stream,
                     wg_w, wg_b, bng_w, bng_b, bng_m, bng_v,
                     wx_w, wx_b, bnx_w, bnx_b, bnx_m, bnx_v,
                     q_w, q_b, k_w, k_b, v_w, v_b,
                     psi_w, psi_b, bnp_w, bnp_b, bnp_m, bnp_v, sa_g,
                     Wcat, Wqkv, bias_c, bias_q, psiw2, scal);

  hipLaunchKernelGGL(conv_qkv_kernel, dim3(512), dim3(256), 0, stream,
                     g, x, Wcat, Wqkv, bias_c, bias_q, c_buf, Qb, Kb, Vb);

  hipLaunchKernelGGL(attn_partial_kernel, dim3(1024), dim3(256), 0, stream,
                     Qb, Kb, Vb, Opart, mlb);

  hipLaunchKernelGGL(combine_kernel, dim3(256), dim3(256), 0, stream,
                     Opart, mlb, c_buf, x, psiw2, scal, out);
}

// Round 3
// 185.622 us; speedup vs baseline: 1.6344x; 1.0178x over previous
//
#include <hip/hip_runtime.h>
#include <hip/hip_bf16.h>

// ---------------------------------------------------------------------------
// AttentionBlockWithSelfAttention on MI355X (gfx950)
// B=4, Cin=128, Fi=64, H=W=64, N=4096, d_qk=8
//
// k1 prep:       fold BN into conv weights (17 blocks)
// k2 conv_qkv:   c = relu(Wcat @ [g;x] + b)  (1024 blocks, n-tile=16)
// k3 attn_part:  flash attention, KV split x8 -> partial O(bf16),m,l (2048 blocks)
// k4 combine:    merge 8 partials + fused epilogue (1024 blocks, 16 q each)
// ---------------------------------------------------------------------------

typedef short bf16x8 __attribute__((ext_vector_type(8)));
typedef unsigned short u16x8 __attribute__((ext_vector_type(8)));
typedef unsigned short u16x4 __attribute__((ext_vector_type(4)));
typedef float f32x4 __attribute__((ext_vector_type(4)));

__device__ __forceinline__ unsigned short f2b(float f) {   // manual RNE (prep only)
  unsigned u = __builtin_bit_cast(unsigned, f);
  u = (u + 0x7FFFu + ((u >> 16) & 1u)) >> 16;
  return (unsigned short)u;
}
// hot-path cvt: let compiler emit v_cvt_pk_bf16_f32 (m240: don't hand-write)
__device__ __forceinline__ unsigned short f2b16(float f) {
  return __builtin_bit_cast(unsigned short, __float2bfloat16(f));
}
__device__ __forceinline__ float b2f(unsigned short u) {
  return __bfloat162float(__builtin_bit_cast(__hip_bfloat16, u));
}

#define EPSV 1e-5f

// ---- workspace layout (bytes) ----
#define WCAT_OFF   0u                      // 64*256 bf16 = 32768
#define WQKV_OFF   32768u                  // 80*64 bf16  = 10240
#define BIASC_OFF  44032u
#define BIASQ_OFF  44288u
#define PSIW_OFF   44608u
#define SCAL_OFF   44864u
#define C_OFF      45056u                  // 4*64*4096 bf16 = 2097152
#define Q_OFF      (C_OFF + 2097152u)      // 4*4096*8 bf16 = 262144
#define K_OFF      (Q_OFF + 262144u)
#define V_OFF      (K_OFF + 262144u)       // 4*64*4096 bf16 = 2097152
#define OPART_OFF  (V_OFF + 2097152u)      // 32*4096*64 bf16 = 16777216
#define ML_OFF     (OPART_OFF + 16777216u) // 32*4096*2 f32 = 1048576  (total ~22.6MB)

// ===========================================================================
__global__ __launch_bounds__(256) void prep_kernel(
    const float* __restrict__ wg_w, const float* __restrict__ wg_b,
    const float* __restrict__ bng_w, const float* __restrict__ bng_b,
    const float* __restrict__ bng_m, const float* __restrict__ bng_v,
    const float* __restrict__ wx_w, const float* __restrict__ wx_b,
    const float* __restrict__ bnx_w, const float* __restrict__ bnx_b,
    const float* __restrict__ bnx_m, const float* __restrict__ bnx_v,
    const float* __restrict__ q_w, const float* __restrict__ q_b,
    const float* __restrict__ k_w, const float* __restrict__ k_b,
    const float* __restrict__ v_w, const float* __restrict__ v_b,
    const float* __restrict__ psi_w, const float* __restrict__ psi_b,
    const float* __restrict__ bnp_w, const float* __restrict__ bnp_b,
    const float* __restrict__ bnp_m, const float* __restrict__ bnp_v,
    const float* __restrict__ sa_gamma,
    unsigned short* __restrict__ Wcat, unsigned short* __restrict__ Wqkv,
    float* __restrict__ bias_c, float* __restrict__ bias_q,
    float* __restrict__ psi_w2, float* __restrict__ scal)
{
  const int t = threadIdx.x;
  const int bid = blockIdx.x;
  if (bid < 16) {
    int o = bid * 4 + (t >> 6);
    int k = (t & 63) * 4;
    float inv;
    const float* src;
    if (k < 128) {
      inv = bng_w[o] * rsqrtf(bng_v[o] + EPSV);
      src = wg_w + o * 128 + k;
    } else {
      inv = bnx_w[o] * rsqrtf(bnx_v[o] + EPSV);
      src = wx_w + o * 128 + (k - 128);
    }
    float4 wv = *(const float4*)src;
    u16x4 pk;
    pk[0] = f2b(wv.x * inv); pk[1] = f2b(wv.y * inv);
    pk[2] = f2b(wv.z * inv); pk[3] = f2b(wv.w * inv);
    *(u16x4*)(Wcat + o * 256 + k) = pk;
    return;
  }
  for (int idx = t; idx < 80 * 64; idx += 256) {
    int r = idx >> 6, k = idx & 63;
    float wv;
    if (r < 8)       wv = q_w[r * 64 + k];
    else if (r < 16) wv = k_w[(r - 8) * 64 + k];
    else             wv = v_w[(r - 16) * 64 + k];
    Wqkv[idx] = f2b(wv);
  }
  if (t < 64) {
    int o = t;
    float invg = bng_w[o] * rsqrtf(bng_v[o] + EPSV);
    float invx = bnx_w[o] * rsqrtf(bnx_v[o] + EPSV);
    bias_c[o] = (wg_b[o] - bng_m[o]) * invg + bng_b[o]
              + (wx_b[o] - bnx_m[o]) * invx + bnx_b[o];
    float invp = bnp_w[0] * rsqrtf(bnp_v[0] + EPSV);
    psi_w2[o] = psi_w[o] * invp;
  }
  if (t < 80)
    bias_q[t] = (t < 8) ? q_b[t] : (t < 16 ? k_b[t - 8] : v_b[t - 16]);
  if (t == 0) {
    float invp = bnp_w[0] * rsqrtf(bnp_v[0] + EPSV);
    scal[0] = sa_gamma[0];
    scal[1] = (psi_b[0] - bnp_m[0]) * invp + bnp_b[0];
  }
}

// ===========================================================================
// conv_qkv: one block per (b, 16-point tile). 1024 blocks, 4 waves.
__global__ __launch_bounds__(256) void conv_qkv_kernel(
    const float* __restrict__ g, const float* __restrict__ x,
    const unsigned short* __restrict__ Wcat, const unsigned short* __restrict__ Wqkv,
    const float* __restrict__ bias_c, const float* __restrict__ bias_q,
    unsigned short* __restrict__ cb, unsigned short* __restrict__ Qb,
    unsigned short* __restrict__ Kb, unsigned short* __restrict__ Vb)
{
  __shared__ __attribute__((aligned(16))) unsigned short xt[16][264];    // [n][k]
  __shared__ __attribute__((aligned(16))) unsigned short clds[16][72];   // [n][o]
  __shared__ __attribute__((aligned(16))) unsigned short vstage[64][20]; // [ch][n]

  const int t = threadIdx.x;
  const int bid = blockIdx.x;
  const int b = bid >> 8;
  const int n0 = (bid & 255) << 4;

  // ---- stage [g;x] tile transposed to [n][k] bf16 ----
  {
    const int col4 = t & 3;          // n offset = col4*4
    const int rowg = t >> 2;         // 0..63 -> rows rowg*4..+3
    float4 v[4];
    #pragma unroll
    for (int rr = 0; rr < 4; ++rr) {
      int row = rowg * 4 + rr;
      const float* src = (row < 128)
          ? (g + ((size_t)(b * 128 + row)) * 4096 + n0 + col4 * 4)
          : (x + ((size_t)(b * 128 + (row - 128))) * 4096 + n0 + col4 * 4);
      v[rr] = *(const float4*)src;
    }
    #pragma unroll
    for (int j = 0; j < 4; ++j) {
      u16x4 pk;
      #pragma unroll
      for (int rr = 0; rr < 4; ++rr)
        pk[rr] = f2b16(((const float*)&v[rr])[j]);
      *(u16x4*)(&xt[col4 * 4 + j][rowg * 4]) = pk;
    }
  }
  __syncthreads();

  const int l = t & 63, w = t >> 6;
  const int l15 = l & 15, lg = l >> 4;
  f32x4 zf = {0.f, 0.f, 0.f, 0.f};

  // ---- conv MFMA: wave w owns o-rows [16w,16w+16) ----
  f32x4 acc = zf;
  const int orow = w * 16 + l15;
  #pragma unroll
  for (int ks = 0; ks < 8; ++ks) {
    bf16x8 af = *(const bf16x8*)(Wcat + orow * 256 + ks * 32 + lg * 8);
    bf16x8 bfv = *(const bf16x8*)(&xt[l15][ks * 32 + lg * 8]);
    acc = __builtin_amdgcn_mfma_f32_16x16x32_bf16(af, bfv, acc, 0, 0, 0);
  }
  #pragma unroll
  for (int r = 0; r < 4; ++r) {
    int o = w * 16 + lg * 4 + r;
    float cv = fmaxf(acc[r] + bias_c[o], 0.f);
    unsigned short cv16 = f2b16(cv);
    cb[((size_t)(b * 64 + o)) * 4096 + n0 + l15] = cv16;
    clds[l15][o] = cv16;
  }
  __syncthreads();

  // ---- QKV MFMA: 5 row-tiles of Wqkv over 4 waves (wave0 takes t5=0,4) ----
  const int ngl = n0 + l15;
  #pragma unroll
  for (int i = 0; i < 2; ++i) {
    int t5 = w + 4 * i;
    if (t5 >= 5) break;
    f32x4 a2 = zf;
    #pragma unroll
    for (int kk = 0; kk < 2; ++kk) {
      bf16x8 af = *(const bf16x8*)(Wqkv + (t5 * 16 + l15) * 64 + kk * 32 + lg * 8);
      bf16x8 bfv = *(const bf16x8*)(&clds[l15][kk * 32 + lg * 8]);
      a2 = __builtin_amdgcn_mfma_f32_16x16x32_bf16(af, bfv, a2, 0, 0, 0);
    }
    if (t5 == 0) {
      // rows lg*4..lg*4+3: lg0/1 -> Q cols 0-3/4-7 ; lg2/3 -> K cols 0-3/4-7
      u16x4 pk;
      #pragma unroll
      for (int r = 0; r < 4; ++r)
        pk[r] = f2b16(a2[r] + bias_q[lg * 4 + r]);
      if (lg < 2)
        *(u16x4*)(Qb + (((size_t)b << 12) + ngl) * 8 + lg * 4) = pk;
      else
        *(u16x4*)(Kb + (((size_t)b << 12) + ngl) * 8 + (lg - 2) * 4) = pk;
    } else {
      #pragma unroll
      for (int r = 0; r < 4; ++r) {
        int row = t5 * 16 + lg * 4 + r;
        int vch = row - 16;
        vstage[vch][l15] = f2b16(a2[r] + bias_q[row]);
      }
    }
  }
  __syncthreads();

  // ---- coalesced V store: 64ch x 16n ----
  {
    int row = t >> 2, seg = t & 3;
    u16x4 pv = *(const u16x4*)(&vstage[row][seg * 4]);
    *(u16x4*)(Vb + ((size_t)(b * 64 + row)) * 4096 + n0 + seg * 4) = pv;
  }
}

// ===========================================================================
// attn_partial: flash attention over one KV chunk of 512. 2048 blocks.
__global__ __launch_bounds__(256) void attn_partial_kernel(
    const unsigned short* __restrict__ Qb, const unsigned short* __restrict__ Kb,
    const unsigned short* __restrict__ Vb,
    unsigned short* __restrict__ Opart, float* __restrict__ ml)
{
  __shared__ __attribute__((aligned(16))) unsigned short klds[64][8];
  __shared__ __attribute__((aligned(16))) unsigned short vlds[64][72];
  __shared__ __attribute__((aligned(16))) unsigned short plds[4][16][72];

  const int t = threadIdx.x;
  const int bid = blockIdx.x;
  const int qt = bid & 63;
  const int b = (bid >> 6) & 3;
  const int ci = bid >> 8;            // KV chunk 0..7 (512 each)
  const int n0 = qt << 6;
  const int l = t & 63, w = t >> 6;
  const int l15 = l & 15, lg = l >> 4;

  bf16x8 qf = {0, 0, 0, 0, 0, 0, 0, 0};
  if (lg == 0)
    qf = *(const bf16x8*)(Qb + (((size_t)b << 12) + n0 + w * 16 + l15) * 8);

  f32x4 zf = {0.f, 0.f, 0.f, 0.f};
  f32x4 O[4];
  O[0] = O[1] = O[2] = O[3] = zf;
  float m_run[4] = {-INFINITY, -INFINITY, -INFINITY, -INFINITY};
  float l_run[4] = {0.f, 0.f, 0.f, 0.f};

  const int m_lo = ci << 9, m_hi = (ci + 1) << 9;
  for (int m0 = m_lo; m0 < m_hi; m0 += 64) {
    if (t < 64)
      *(int4*)(&klds[t][0]) = *(const int4*)(Kb + (((size_t)b << 12) + m0 + t) * 8);
    #pragma unroll
    for (int i = 0; i < 2; ++i) {
      int ci2 = t + 256 * i;
      int row = ci2 >> 3, off = ci2 & 7;
      *(int4*)(&vlds[row][off * 8]) =
          *(const int4*)(Vb + ((size_t)(b * 64 + row)) * 4096 + m0 + off * 8);
    }
    __syncthreads();

    f32x4 e[4];
    #pragma unroll
    for (int mt = 0; mt < 4; ++mt) {
      bf16x8 kf = *(const bf16x8*)(&klds[mt * 16 + l15][0]);
      e[mt] = __builtin_amdgcn_mfma_f32_16x16x32_bf16(qf, kf, zf, 0, 0, 0);
    }

    #pragma unroll
    for (int r = 0; r < 4; ++r) {
      float vm = fmaxf(fmaxf(e[0][r], e[1][r]), fmaxf(e[2][r], e[3][r]));
      vm = fmaxf(vm, __shfl_xor(vm, 1));
      vm = fmaxf(vm, __shfl_xor(vm, 2));
      vm = fmaxf(vm, __shfl_xor(vm, 4));
      vm = fmaxf(vm, __shfl_xor(vm, 8));
      float nm = fmaxf(m_run[r], vm);
      float sc = __expf(m_run[r] - nm);
      float s = 0.f;
      #pragma unroll
      for (int mt = 0; mt < 4; ++mt) {
        float p = __expf(e[mt][r] - nm);
        e[mt][r] = p;
        s += p;
      }
      s += __shfl_xor(s, 1);
      s += __shfl_xor(s, 2);
      s += __shfl_xor(s, 4);
      s += __shfl_xor(s, 8);
      l_run[r] = l_run[r] * sc + s;
      m_run[r] = nm;
      #pragma unroll
      for (int mt = 0; mt < 4; ++mt)
        plds[w][lg * 4 + r][mt * 16 + l15] = f2b16(e[mt][r]);
      #pragma unroll
      for (int ct = 0; ct < 4; ++ct) O[ct][r] *= sc;
    }

    #pragma unroll
    for (int ct = 0; ct < 4; ++ct) {
      #pragma unroll
      for (int kk = 0; kk < 2; ++kk) {
        bf16x8 pa = *(const bf16x8*)(&plds[w][l15][kk * 32 + lg * 8]);
        bf16x8 vb = *(const bf16x8*)(&vlds[ct * 16 + l15][kk * 32 + lg * 8]);
        O[ct] = __builtin_amdgcn_mfma_f32_16x16x32_bf16(pa, vb, O[ct], 0, 0, 0);
      }
    }
    __syncthreads();
  }

  // ---- store partials: O bf16 (unnormalized) + (m,l) f32 ----
  const size_t pb = ((size_t)(ci * 4 + b)) << 12;
  #pragma unroll
  for (int ct = 0; ct < 4; ++ct) {
    int ch = ct * 16 + l15;
    #pragma unroll
    for (int r = 0; r < 4; ++r) {
      int qg = n0 + w * 16 + lg * 4 + r;
      Opart[(pb + qg) * 64 + ch] = f2b16(O[ct][r]);
    }
  }
  if (l15 == 0) {
    #pragma unroll
    for (int r = 0; r < 4; ++r) {
      int qg = n0 + w * 16 + lg * 4 + r;
      float2 mv;
      mv.x = m_run[r]; mv.y = l_run[r];
      *(float2*)(ml + (pb + qg) * 2) = mv;
    }
  }
}

// ===========================================================================
// combine: merge 8 KV-chunk partials + fused epilogue. 1024 blocks, 16 q each.
__global__ __launch_bounds__(256) void combine_kernel(
    const unsigned short* __restrict__ Opart, const float* __restrict__ ml,
    const unsigned short* __restrict__ cb, const float* __restrict__ xin,
    const float* __restrict__ psi_w2, const float* __restrict__ scal,
    float* __restrict__ out)
{
  __shared__ __attribute__((aligned(16))) unsigned short c_lds[64][20]; // [ch][n]
  __shared__ __attribute__((aligned(8))) float2 ml_lds[16][8];
  __shared__ float psi_lds[16];

  const int t = threadIdx.x;
  const int bid = blockIdx.x;
  const int b = bid >> 8;
  const int n0 = (bid & 255) << 4;

  // stage c tile [64ch][16n] bf16
  {
    int row = t >> 2, seg = t & 3;
    *(u16x4*)(&c_lds[row][seg * 4]) =
        *(const u16x4*)(cb + ((size_t)(b * 64 + row)) * 4096 + n0 + seg * 4);
  }
  // stage ml [16q][8ci]
  if (t < 128) {
    int q = t >> 3, ci = t & 7;
    ml_lds[q][ci] = *(const float2*)(ml + ((((size_t)(ci * 4 + b)) << 12) + n0 + q) * 2);
  }
  __syncthreads();

  const int q = t >> 4, cg = t & 15;
  const int qg = n0 + q;

  float M = -INFINITY;
  #pragma unroll
  for (int ci = 0; ci < 8; ++ci) M = fmaxf(M, ml_lds[q][ci].x);
  float L = 0.f, wgt[8];
  #pragma unroll
  for (int ci = 0; ci < 8; ++ci) {
    wgt[ci] = __expf(ml_lds[q][ci].x - M);
    L += wgt[ci] * ml_lds[q][ci].y;
  }
  float o4[4] = {0.f, 0.f, 0.f, 0.f};
  #pragma unroll
  for (int ci = 0; ci < 8; ++ci) {
    u16x4 p = *(const u16x4*)(Opart + ((((size_t)(ci * 4 + b)) << 12) + qg) * 64 + cg * 4);
    float wv = wgt[ci];
    #pragma unroll
    for (int k = 0; k < 4; ++k) o4[k] += wv * b2f(p[k]);
  }
  const float invL = 1.f / L;
  const float gamma = scal[0], psi_c = scal[1];
  float ps = 0.f;
  #pragma unroll
  for (int k = 0; k < 4; ++k) {
    int ch = cg * 4 + k;
    ps += psi_w2[ch] * (gamma * (o4[k] * invL) + b2f(c_lds[ch][q]));
  }
  ps += __shfl_xor(ps, 1);
  ps += __shfl_xor(ps, 2);
  ps += __shfl_xor(ps, 4);
  ps += __shfl_xor(ps, 8);
  if (cg == 0)
    psi_lds[q] = 1.f / (1.f + __expf(-(ps + psi_c)));
  __syncthreads();

  // out = x * psi : 128f x 16n
  #pragma unroll
  for (int i = 0; i < 2; ++i) {
    int idx = t + 256 * i;
    int f = idx >> 2, c4 = idx & 3;
    size_t off = ((size_t)(b * 128 + f)) * 4096 + n0 + c4 * 4;
    float4 xv = *(const float4*)(xin + off);
    float4 ov;
    ov.x = xv.x * psi_lds[c4 * 4 + 0];
    ov.y = xv.y * psi_lds[c4 * 4 + 1];
    ov.z = xv.z * psi_lds[c4 * 4 + 2];
    ov.w = xv.w * psi_lds[c4 * 4 + 3];
    *(float4*)(out + off) = ov;
  }
}

// ===========================================================================
extern "C" void kernel_launch(void* const* d_in, const int* in_sizes, int n_in,
                              void* d_out, int out_size, void* d_ws, size_t ws_size,
                              hipStream_t stream) {
  (void)in_sizes; (void)n_in; (void)out_size; (void)ws_size;
  const float* g     = (const float*)d_in[0];
  const float* x     = (const float*)d_in[1];
  const float* wg_w  = (const float*)d_in[2];
  const float* wg_b  = (const float*)d_in[3];
  const float* bng_w = (const float*)d_in[4];
  const float* bng_b = (const float*)d_in[5];
  const float* bng_m = (const float*)d_in[6];
  const float* bng_v = (const float*)d_in[7];
  const float* wx_w  = (const float*)d_in[8];
  const float* wx_b  = (const float*)d_in[9];
  const float* bnx_w = (const float*)d_in[10];
  const float* bnx_b = (const float*)d_in[11];
  const float* bnx_m = (const float*)d_in[12];
  const float* bnx_v = (const float*)d_in[13];
  const float* q_w   = (const float*)d_in[14];
  const float* q_b   = (const float*)d_in[15];
  const float* k_w   = (const float*)d_in[16];
  const float* k_b   = (const float*)d_in[17];
  const float* v_w   = (const float*)d_in[18];
  const float* v_b   = (const float*)d_in[19];
  const float* sa_g  = (const float*)d_in[20];
  const float* psi_w = (const float*)d_in[21];
  const float* psi_b = (const float*)d_in[22];
  const float* bnp_w = (const float*)d_in[23];
  const float* bnp_b = (const float*)d_in[24];
  const float* bnp_m = (const float*)d_in[25];
  const float* bnp_v = (const float*)d_in[26];
  float* out = (float*)d_out;

  char* ws = (char*)d_ws;
  unsigned short* Wcat = (unsigned short*)(ws + WCAT_OFF);
  unsigned short* Wqkv = (unsigned short*)(ws + WQKV_OFF);
  float* bias_c = (float*)(ws + BIASC_OFF);
  float* bias_q = (float*)(ws + BIASQ_OFF);
  float* psiw2  = (float*)(ws + PSIW_OFF);
  float* scal   = (float*)(ws + SCAL_OFF);
  unsigned short* cb = (unsigned short*)(ws + C_OFF);
  unsigned short* Qb = (unsigned short*)(ws + Q_OFF);
  unsigned short* Kb = (unsigned short*)(ws + K_OFF);
  unsigned short* Vb = (unsigned short*)(ws + V_OFF);
  unsigned short* Opart = (unsigned short*)(ws + OPART_OFF);
  float* mlb   = (float*)(ws + ML_OFF);

  hipLaunchKernelGGL(prep_kernel, dim3(17), dim3(256), 0, stream,
                     wg_w, wg_b, bng_w, bng_b, bng_m, bng_v,
                     wx_w, wx_b, bnx_w, bnx_b, bnx_m, bnx_v,
                     q_w, q_b, k_w, k_b, v_w, v_b,
                     psi_w, psi_b, bnp_w, bnp_b, bnp_m, bnp_v, sa_g,
                     Wcat, Wqkv, bias_c, bias_q, psiw2, scal);

  hipLaunchKernelGGL(conv_qkv_kernel, dim3(1024), dim3(256), 0, stream,
                     g, x, Wcat, Wqkv, bias_c, bias_q, cb, Qb, Kb, Vb);

  hipLaunchKernelGGL(attn_partial_kernel, dim3(2048), dim3(256), 0, stream,
                     Qb, Kb, Vb, Opart, mlb);

  hipLaunchKernelGGL(combine_kernel, dim3(1024), dim3(256), 0, stream,
                     Opart, mlb, cb, x, psiw2, scal, out);
}